// Round 2
// baseline (8933.682 us; speedup 1.0000x reference)
//
#include <hip/hip_runtime.h>

// ---------------------------------------------------------------------------
// SQLDecoder: 48-step recurrent decoder with dot-product attention.
//   * scores = src @ (h @ W_att)  -- never materialize src_lin [B,S,H]
//   * single-pass online-softmax attention (K == V == src), src cached as bf16
//   * bf16 MFMA GEMMs, fp32 cell/readout; LSTM fused into gates-GEMM epilogue
//   * per-t action/type embeddings precomputed (xaty); state double-buffered
// B=256 S=512 E=H=AV=1024 A=TY=128 T=48 NP=97 K_state=2048 K_aty=256
// ---------------------------------------------------------------------------

typedef short s16x8 __attribute__((ext_vector_type(8)));
typedef float f32x4 __attribute__((ext_vector_type(4)));

__device__ __forceinline__ unsigned short f2b(float x) {
  unsigned int u = __float_as_uint(x);
  return (unsigned short)((u + 0x7fffu + ((u >> 16) & 1u)) >> 16);  // RNE
}
__device__ __forceinline__ float b2f(unsigned short h) {
  return __uint_as_float(((unsigned int)h) << 16);
}
__device__ __forceinline__ float sigm(float x) { return 1.f / (1.f + __expf(-x)); }

// ---------------- prep kernels ----------------------------------------------

// max-pool over s + bf16 conversion of src. grid = B*4, block=256. unroll-8.
template <int WRITE_B16>
__global__ __launch_bounds__(256) void pool_convert(const float* __restrict__ src,
                                                    unsigned short* __restrict__ srcb,
                                                    unsigned short* __restrict__ pooledb) {
  int b = blockIdx.x >> 2;
  int e = (blockIdx.x & 3) * 256 + threadIdx.x;
  const float* p = src + (size_t)b * 524288 + e;
  float m = -3e38f;
  for (int s = 0; s < 512; s += 8) {
    float v[8];
#pragma unroll
    for (int i = 0; i < 8; ++i) v[i] = p[(size_t)(s + i) * 1024];
#pragma unroll
    for (int i = 0; i < 8; ++i) {
      m = fmaxf(m, v[i]);
      if (WRITE_B16) srcb[(size_t)b * 524288 + (size_t)(s + i) * 1024 + e] = f2b(v[i]);
    }
  }
  pooledb[b * 1024 + e] = f2b(m);
}

// Wcat rows permuted n' = j*4+g (g: 0=i,1=f,2=g,3=o); cols = [att|h|a|ty].
__global__ __launch_bounds__(256) void conv_wcat(const float* __restrict__ wih,
                                                 const float* __restrict__ whh,
                                                 unsigned short* __restrict__ wcat) {
  int idx = blockIdx.x * 256 + threadIdx.x;  // 4096*2304
  int np = idx / 2304;
  int k = idx - np * 2304;
  int j = np >> 2, g = np & 3;
  int n = g * 1024 + j;  // original gate row
  float v;
  if (k < 1024) v = wih[n * 1280 + 128 + k];          // att slice of x
  else if (k < 2048) v = whh[n * 1024 + (k - 1024)];  // h
  else if (k < 2176) v = wih[n * 1280 + (k - 2048)];  // action embed
  else v = wih[n * 1280 + 1152 + (k - 2176)];         // type embed
  wcat[idx] = f2b(v);
}

// combined permuted bias  bsum[j*4+g] = b_ih[g*1024+j] + b_hh[g*1024+j]
__global__ __launch_bounds__(256) void conv_bsum(const float* __restrict__ bih,
                                                 const float* __restrict__ bhh,
                                                 float* __restrict__ bsum) {
  int idx = blockIdx.x * 256 + threadIdx.x;  // 4096
  int j = idx >> 2, g = idx & 3;
  int n = g * 1024 + j;
  bsum[idx] = bih[n] + bhh[n];
}

// W_att [H,E] -> bf16 [E,H]
__global__ __launch_bounds__(256) void conv_wattT(const float* __restrict__ watt,
                                                  unsigned short* __restrict__ wt) {
  int idx = blockIdx.x * 256 + threadIdx.x;  // 1024*1024
  int e = idx >> 10, h = idx & 1023;
  wt[idx] = f2b(watt[h * 1024 + e]);
}

__global__ __launch_bounds__(256) void conv_f2b(const float* __restrict__ s,
                                                unsigned short* __restrict__ d, int n) {
  int idx = blockIdx.x * 256 + threadIdx.x;
  if (idx < n) d[idx] = f2b(s[idx]);
}

// W_qa [A=128, K=1024] -> fp32 [K=1024, 128]
__global__ __launch_bounds__(256) void conv_wqaT(const float* __restrict__ wqa,
                                                 float* __restrict__ wt) {
  int idx = blockIdx.x * 256 + threadIdx.x;  // 131072
  int k = idx >> 7, j = idx & 127;
  wt[idx] = wqa[j * 1024 + k];
}

// per-step action/type embedding slices; t=0 masked to zero
__global__ __launch_bounds__(256) void conv_xaty(const int* __restrict__ action,
                                                 const int* __restrict__ type_ids,
                                                 const float* __restrict__ prod_emb,
                                                 const float* __restrict__ type_emb,
                                                 unsigned short* __restrict__ xaty) {
  int idx = blockIdx.x * 256 + threadIdx.x;  // 48*256*256
  int t = idx >> 16;
  int b = (idx >> 8) & 255;
  int kk = idx & 255;
  float v = 0.f;
  if (t > 0) {
    if (kk < 128) v = prod_emb[action[t * 256 + b] * 128 + kk];
    else v = type_emb[type_ids[t * 256 + b] * 128 + (kk - 128)];
  }
  xaty[idx] = f2b(v);
}

// zero xstate0 att slice + c state
__global__ __launch_bounds__(256) void init0(unsigned short* __restrict__ xs0,
                                             float* __restrict__ c) {
  int idx = blockIdx.x * 256 + threadIdx.x;  // 262144
  int b = idx >> 10, e = idx & 1023;
  xs0[(size_t)b * 2048 + e] = 0;
  c[idx] = 0.f;
}

// ---------------- GEMM (generic, compile-time K) ----------------------------
// C[m,n] = sum_k A[m,k]*Bt[n,k]; A,Bt bf16 K-contiguous. 4 waves, 64x64 tile.
// EPI 0: C fp32. EPI 1: tanh -> C fp32 + bf16 aux. EPI 2: tanh(acc+bias) -> bf16 aux.
template <int EPI, int K>
__global__ __launch_bounds__(256) void gemm_bt(const unsigned short* __restrict__ A, int lda,
                                               const unsigned short* __restrict__ B, int ldb,
                                               float* __restrict__ C, int ldc,
                                               const float* __restrict__ bias,
                                               unsigned short* __restrict__ aux, int aux_ld,
                                               int aux_off) {
  int lane = threadIdx.x & 63;
  int wid = threadIdx.x >> 6;
  int mw = blockIdx.y * 64 + (wid >> 1) * 32;
  int nw = blockIdx.x * 64 + (wid & 1) * 32;
  int lr = lane & 15;
  int kg = lane >> 4;
  const unsigned short* a0p = A + (size_t)(mw + lr) * lda + kg * 8;
  const unsigned short* a1p = a0p + (size_t)16 * lda;
  const unsigned short* b0p = B + (size_t)(nw + lr) * ldb + kg * 8;
  const unsigned short* b1p = b0p + (size_t)16 * ldb;
  f32x4 acc00 = {0.f, 0.f, 0.f, 0.f};
  f32x4 acc01 = acc00, acc10 = acc00, acc11 = acc00;
#pragma unroll 4
  for (int k = 0; k < K; k += 32) {
    s16x8 a0 = *(const s16x8*)(a0p + k);
    s16x8 a1 = *(const s16x8*)(a1p + k);
    s16x8 b0 = *(const s16x8*)(b0p + k);
    s16x8 b1 = *(const s16x8*)(b1p + k);
    acc00 = __builtin_amdgcn_mfma_f32_16x16x32_bf16(a0, b0, acc00, 0, 0, 0);
    acc01 = __builtin_amdgcn_mfma_f32_16x16x32_bf16(a0, b1, acc01, 0, 0, 0);
    acc10 = __builtin_amdgcn_mfma_f32_16x16x32_bf16(a1, b0, acc10, 0, 0, 0);
    acc11 = __builtin_amdgcn_mfma_f32_16x16x32_bf16(a1, b1, acc11, 0, 0, 0);
  }
  int r0 = mw + kg * 4;  // C/D: col = lane&15, row = (lane>>4)*4 + r
  int c0 = nw + lr;
#pragma unroll
  for (int fi = 0; fi < 2; ++fi) {
#pragma unroll
    for (int fj = 0; fj < 2; ++fj) {
      f32x4 acc = (fi == 0) ? (fj == 0 ? acc00 : acc01) : (fj == 0 ? acc10 : acc11);
      int rr = r0 + fi * 16;
      int cc = c0 + fj * 16;
#pragma unroll
      for (int r = 0; r < 4; ++r) {
        float v = acc[r];
        if constexpr (EPI == 2) v = tanhf(v + bias[cc]);
        if constexpr (EPI == 1) v = tanhf(v);
        if constexpr (EPI != 0) aux[(size_t)(rr + r) * aux_ld + aux_off + cc] = f2b(v);
        if constexpr (EPI != 2) C[(size_t)(rr + r) * ldc + cc] = v;
      }
    }
  }
}

// ---------------- gates GEMM + fused LSTM cell ------------------------------
// A rows: [xin(att|h) 2048 | xaty 256]; B = wcat permuted (n'=j*4+g).
// grid (64,4), 256 thr. Epilogue recombines i,f,g,o via LDS, updates c,
// writes h bf16 to xout h-slice (next step) and a2 h-slice (this step).
__global__ __launch_bounds__(256) void gates_fused(const unsigned short* __restrict__ xin,
                                                   const unsigned short* __restrict__ xaty,
                                                   const unsigned short* __restrict__ wcat,
                                                   const float* __restrict__ bsum,
                                                   float* __restrict__ cbuf,
                                                   unsigned short* __restrict__ xout,
                                                   unsigned short* __restrict__ a2) {
  __shared__ float ld[64][68];
  int lane = threadIdx.x & 63;
  int wid = threadIdx.x >> 6;
  int mwl = (wid >> 1) * 32;
  int nwl = (wid & 1) * 32;
  int mw = blockIdx.y * 64 + mwl;
  int nw = blockIdx.x * 64 + nwl;
  int lr = lane & 15;
  int kg = lane >> 4;
  const unsigned short* a0p = xin + (size_t)(mw + lr) * 2048 + kg * 8;
  const unsigned short* a1p = a0p + (size_t)16 * 2048;
  const unsigned short* b0p = wcat + (size_t)(nw + lr) * 2304 + kg * 8;
  const unsigned short* b1p = b0p + (size_t)16 * 2304;
  f32x4 acc00 = {0.f, 0.f, 0.f, 0.f};
  f32x4 acc01 = acc00, acc10 = acc00, acc11 = acc00;
#pragma unroll 4
  for (int k = 0; k < 2048; k += 32) {
    s16x8 a0 = *(const s16x8*)(a0p + k);
    s16x8 a1 = *(const s16x8*)(a1p + k);
    s16x8 b0 = *(const s16x8*)(b0p + k);
    s16x8 b1 = *(const s16x8*)(b1p + k);
    acc00 = __builtin_amdgcn_mfma_f32_16x16x32_bf16(a0, b0, acc00, 0, 0, 0);
    acc01 = __builtin_amdgcn_mfma_f32_16x16x32_bf16(a0, b1, acc01, 0, 0, 0);
    acc10 = __builtin_amdgcn_mfma_f32_16x16x32_bf16(a1, b0, acc10, 0, 0, 0);
    acc11 = __builtin_amdgcn_mfma_f32_16x16x32_bf16(a1, b1, acc11, 0, 0, 0);
  }
  const unsigned short* c0p = xaty + (size_t)(mw + lr) * 256 + kg * 8;
  const unsigned short* c1p = c0p + (size_t)16 * 256;
#pragma unroll
  for (int k = 0; k < 256; k += 32) {
    s16x8 a0 = *(const s16x8*)(c0p + k);
    s16x8 a1 = *(const s16x8*)(c1p + k);
    s16x8 b0 = *(const s16x8*)(b0p + 2048 + k);
    s16x8 b1 = *(const s16x8*)(b1p + 2048 + k);
    acc00 = __builtin_amdgcn_mfma_f32_16x16x32_bf16(a0, b0, acc00, 0, 0, 0);
    acc01 = __builtin_amdgcn_mfma_f32_16x16x32_bf16(a0, b1, acc01, 0, 0, 0);
    acc10 = __builtin_amdgcn_mfma_f32_16x16x32_bf16(a1, b0, acc10, 0, 0, 0);
    acc11 = __builtin_amdgcn_mfma_f32_16x16x32_bf16(a1, b1, acc11, 0, 0, 0);
  }
  // stage 64x64 fp32 gate tile to LDS
  int r0 = mwl + kg * 4;
  int c0 = nwl + lr;
#pragma unroll
  for (int fi = 0; fi < 2; ++fi)
#pragma unroll
    for (int fj = 0; fj < 2; ++fj) {
      f32x4 acc = (fi == 0) ? (fj == 0 ? acc00 : acc01) : (fj == 0 ? acc10 : acc11);
#pragma unroll
      for (int r = 0; r < 4; ++r) ld[r0 + fi * 16 + r][c0 + fj * 16] = acc[r];
    }
  __syncthreads();
  // each thread: 1 batch row, 4 consecutive j units (16 gate values)
  int row = threadIdx.x >> 2;
  int col0 = (threadIdx.x & 3) * 16;
  int b = blockIdx.y * 64 + row;
  int jbase = blockIdx.x * 16 + (threadIdx.x & 3) * 4;
  float4 cold = *(const float4*)(cbuf + (size_t)b * 1024 + jbase);
  float cn[4];
  unsigned short hb[4];
#pragma unroll
  for (int i = 0; i < 4; ++i) {
    float4 bs = *(const float4*)(bsum + (size_t)(jbase + i) * 4);
    float vi = ld[row][col0 + 4 * i + 0] + bs.x;
    float vf = ld[row][col0 + 4 * i + 1] + bs.y;
    float vg = ld[row][col0 + 4 * i + 2] + bs.z;
    float vo = ld[row][col0 + 4 * i + 3] + bs.w;
    float co = (i == 0) ? cold.x : (i == 1) ? cold.y : (i == 2) ? cold.z : cold.w;
    float ct = sigm(vf) * co + sigm(vi) * tanhf(vg);
    float ht = sigm(vo) * tanhf(ct);
    cn[i] = ct;
    hb[i] = f2b(ht);
  }
  *(float4*)(cbuf + (size_t)b * 1024 + jbase) = make_float4(cn[0], cn[1], cn[2], cn[3]);
  ushort4 h4 = make_ushort4(hb[0], hb[1], hb[2], hb[3]);
  *(ushort4*)(xout + (size_t)b * 2048 + 1024 + jbase) = h4;
  *(ushort4*)(a2 + (size_t)b * 2048 + jbase) = h4;
}

// ---------------- flash attention (single pass, K==V==src) ------------------
template <int BF16P>
__global__ __launch_bounds__(1024) void flash_attn(const unsigned short* __restrict__ srcb,
                                                   const float* __restrict__ srcf,
                                                   const float* __restrict__ q,
                                                   unsigned short* __restrict__ a2) {
  __shared__ unsigned short lctx[16][1024];
  __shared__ float lm[16], ldn[16], lsc[16];
  __shared__ float sDinv;
  int b = blockIdx.x;
  int wid = threadIdx.x >> 6, lane = threadIdx.x & 63;
  float qr[16];
  {
    const float4* qp = (const float4*)(q + (size_t)b * 1024 + lane * 16);
#pragma unroll
    for (int i = 0; i < 4; ++i) {
      float4 t = qp[i];
      qr[4 * i] = t.x; qr[4 * i + 1] = t.y; qr[4 * i + 2] = t.z; qr[4 * i + 3] = t.w;
    }
  }
  float m = -3e38f, d = 0.f;
  float ctx[16];
#pragma unroll
  for (int i = 0; i < 16; ++i) ctx[i] = 0.f;
  int s0 = wid * 32;

  if (BF16P) {
    const unsigned short* rb = srcb + (size_t)b * 524288 + lane * 16;
    s16x8 u0 = *(const s16x8*)(rb + (size_t)s0 * 1024);
    s16x8 u1 = *(const s16x8*)(rb + (size_t)s0 * 1024 + 8);
    for (int s = 0; s < 32; ++s) {
      int rn = s0 + s + 1;
      rn = rn > 511 ? 511 : rn;
      s16x8 n0 = *(const s16x8*)(rb + (size_t)rn * 1024);
      s16x8 n1 = *(const s16x8*)(rb + (size_t)rn * 1024 + 8);
      float v[16];
#pragma unroll
      for (int i = 0; i < 8; ++i) {
        v[i] = b2f((unsigned short)u0[i]);
        v[8 + i] = b2f((unsigned short)u1[i]);
      }
      float sc = 0.f;
#pragma unroll
      for (int i = 0; i < 16; ++i) sc += v[i] * qr[i];
#pragma unroll
      for (int off = 1; off < 64; off <<= 1) sc += __shfl_xor(sc, off);
      float mn = fmaxf(m, sc);
      float scale = __expf(m - mn);
      float wgt = __expf(sc - mn);
      d = d * scale + wgt;
#pragma unroll
      for (int i = 0; i < 16; ++i) ctx[i] = ctx[i] * scale + wgt * v[i];
      m = mn;
      u0 = n0; u1 = n1;
    }
  } else {
    const float* rb = srcf + (size_t)b * 524288 + lane * 16;
    for (int s = 0; s < 32; ++s) {
      int r = s0 + s;
      float v[16];
#pragma unroll
      for (int i = 0; i < 4; ++i) {
        float4 t = *(const float4*)(rb + (size_t)r * 1024 + 4 * i);
        v[4 * i] = t.x; v[4 * i + 1] = t.y; v[4 * i + 2] = t.z; v[4 * i + 3] = t.w;
      }
      float sc = 0.f;
#pragma unroll
      for (int i = 0; i < 16; ++i) sc += v[i] * qr[i];
#pragma unroll
      for (int off = 1; off < 64; off <<= 1) sc += __shfl_xor(sc, off);
      float mn = fmaxf(m, sc);
      float scale = __expf(m - mn);
      float wgt = __expf(sc - mn);
      d = d * scale + wgt;
#pragma unroll
      for (int i = 0; i < 16; ++i) ctx[i] = ctx[i] * scale + wgt * v[i];
      m = mn;
    }
  }

#pragma unroll
  for (int i = 0; i < 16; ++i) lctx[wid][lane * 16 + i] = f2b(ctx[i]);
  if (lane == 0) { lm[wid] = m; ldn[wid] = d; }
  __syncthreads();
  if (threadIdx.x == 0) {
    float M = lm[0];
    for (int w2 = 1; w2 < 16; ++w2) M = fmaxf(M, lm[w2]);
    float D = 0.f;
    for (int w2 = 0; w2 < 16; ++w2) {
      float sc = __expf(lm[w2] - M);
      lsc[w2] = sc;
      D += sc * ldn[w2];
    }
    sDinv = 1.f / D;
  }
  __syncthreads();
  int e = threadIdx.x;
  float acc = 0.f;
#pragma unroll
  for (int w2 = 0; w2 < 16; ++w2) acc += lsc[w2] * b2f(lctx[w2][e]);
  a2[(size_t)b * 2048 + 1024 + e] = f2b(acc * sDinv);
}

// ---------------- readout ---------------------------------------------------
__global__ __launch_bounds__(128) void readout(const float* __restrict__ att,
                                               const float* __restrict__ wqaT,
                                               const float* __restrict__ b_qa,
                                               const float* __restrict__ prod_emb,
                                               const float* __restrict__ prod_bias,
                                               float* __restrict__ out, int t) {
  __shared__ float s_att[1024], s_q2[128], s_log[97], s_red[2];
  int b = blockIdx.x;
  int tid = threadIdx.x;
  for (int i = tid; i < 1024; i += 128) s_att[i] = att[(size_t)b * 1024 + i];
  __syncthreads();
  float acc = b_qa[tid];
  for (int k = 0; k < 1024; ++k) acc += s_att[k] * wqaT[k * 128 + tid];
  s_q2[tid] = tanhf(acc);
  __syncthreads();
  if (tid < 97) {
    float a = prod_bias[tid];
    const float* pe = prod_emb + tid * 128;
    for (int k = 0; k < 128; ++k) a += s_q2[k] * pe[k];
    s_log[tid] = a;
  }
  __syncthreads();
  if (tid == 0) {
    float M = s_log[0];
    for (int k = 1; k < 97; ++k) M = fmaxf(M, s_log[k]);
    float D = 0.f;
    for (int k = 0; k < 97; ++k) D += __expf(s_log[k] - M);
    s_red[0] = M;
    s_red[1] = D;
  }
  __syncthreads();
  if (tid < 97)
    out[((size_t)t * 256 + b) * 97 + tid] = __expf(s_log[tid] - s_red[0]) / s_red[1];
}

// ---------------------------------------------------------------------------

extern "C" void kernel_launch(void* const* d_in, const int* in_sizes, int n_in,
                              void* d_out, int out_size, void* d_ws, size_t ws_size,
                              hipStream_t stream) {
  const float* src = (const float*)d_in[0];
  const int* action = (const int*)d_in[1];
  const int* type_ids = (const int*)d_in[2];
  const float* W_ih = (const float*)d_in[3];
  const float* b_ih = (const float*)d_in[4];
  const float* W_hh = (const float*)d_in[5];
  const float* b_hh = (const float*)d_in[6];
  const float* W_att = (const float*)d_in[7];
  const float* W_av = (const float*)d_in[8];
  const float* W_qa = (const float*)d_in[9];
  const float* b_qa = (const float*)d_in[10];
  const float* prod_emb = (const float*)d_in[11];
  const float* prod_bias = (const float*)d_in[12];
  const float* type_emb = (const float*)d_in[13];
  const float* W_init = (const float*)d_in[14];
  const float* b_init = (const float*)d_in[15];
  float* out = (float*)d_out;

  const size_t NEED_SMALL = 40910848ull;
  const size_t NEED_BIG = 309346304ull;  // + bf16 src copy
  bool big = ws_size >= NEED_BIG;
  if (!big && ws_size < NEED_SMALL) return;

  char* w = (char*)d_ws;
  size_t o = 0;
  unsigned short* wcat = (unsigned short*)(w + o); o += 18874368ull;
  unsigned short* wattT = (unsigned short*)(w + o); o += 2097152ull;
  unsigned short* wav = (unsigned short*)(w + o); o += 4194304ull;
  float* wqaT = (float*)(w + o); o += 524288ull;
  unsigned short* xaty = (unsigned short*)(w + o); o += 6291456ull;   // [48][256][256]
  unsigned short* xstate0 = (unsigned short*)(w + o); o += 1048576ull;  // [256][2048] att|h
  unsigned short* xstate1 = (unsigned short*)(w + o); o += 1048576ull;
  unsigned short* a2 = (unsigned short*)(w + o); o += 1048576ull;       // [256][2048] h|ctx
  float* cbuf = (float*)(w + o); o += 1048576ull;
  float* qbuf = (float*)(w + o); o += 1048576ull;
  float* attf = (float*)(w + o); o += 1048576ull;
  unsigned short* pooledb = (unsigned short*)(w + o); o += 524288ull;
  unsigned short* winitb = (unsigned short*)(w + o); o += 2097152ull;
  float* bsum = (float*)(w + o); o += 16384ull;
  unsigned short* srcb = nullptr;
  if (big) { srcb = (unsigned short*)(w + o); o += 268435456ull; }

  // ---- prep ----
  if (big) pool_convert<1><<<1024, 256, 0, stream>>>(src, srcb, pooledb);
  else     pool_convert<0><<<1024, 256, 0, stream>>>(src, nullptr, pooledb);
  conv_wcat<<<36864, 256, 0, stream>>>(W_ih, W_hh, wcat);
  conv_bsum<<<16, 256, 0, stream>>>(b_ih, b_hh, bsum);
  conv_wattT<<<4096, 256, 0, stream>>>(W_att, wattT);
  conv_f2b<<<8192, 256, 0, stream>>>(W_av, wav, 2097152);
  conv_f2b<<<4096, 256, 0, stream>>>(W_init, winitb, 1048576);
  conv_wqaT<<<512, 256, 0, stream>>>(W_qa, wqaT);
  conv_xaty<<<12288, 256, 0, stream>>>(action, type_ids, prod_emb, type_emb, xaty);
  init0<<<1024, 256, 0, stream>>>(xstate0, cbuf);
  // h0 = tanh(pooled @ W_init.T + b_init) -> xstate0 h-slice (bf16 MFMA)
  gemm_bt<2, 1024><<<dim3(16, 4), 256, 0, stream>>>(pooledb, 1024, winitb, 1024,
                                                    nullptr, 0, b_init, xstate0, 2048, 1024);

  // ---- 48 recurrent steps ----
  for (int t = 0; t < 48; ++t) {
    const unsigned short* xin = (t & 1) ? xstate1 : xstate0;
    unsigned short* xout = (t & 1) ? xstate0 : xstate1;
    gates_fused<<<dim3(64, 4), 256, 0, stream>>>(xin, xaty + (size_t)t * 65536, wcat, bsum,
                                                 cbuf, xout, a2);
    // q = h @ W_att
    gemm_bt<0, 1024><<<dim3(16, 4), 256, 0, stream>>>(a2, 2048, wattT, 1024, qbuf, 1024,
                                                      nullptr, nullptr, 0, 0);
    if (big) flash_attn<1><<<256, 1024, 0, stream>>>(srcb, nullptr, qbuf, a2);
    else     flash_attn<0><<<256, 1024, 0, stream>>>(nullptr, src, qbuf, a2);
    // att = tanh([h|ctx] @ W_av^T) -> attf fp32 + bf16 into xout att-slice
    gemm_bt<1, 2048><<<dim3(16, 4), 256, 0, stream>>>(a2, 2048, wav, 2048, attf, 1024,
                                                      nullptr, xout, 2048, 0);
    readout<<<256, 128, 0, stream>>>(attf, wqaT, b_qa, prod_emb, prod_bias, out, t);
  }
}

// Round 4
// 6820.888 us; speedup vs baseline: 1.3098x; 1.3098x over previous
//
#include <hip/hip_runtime.h>

// ---------------------------------------------------------------------------
// SQLDecoder: 48-step recurrent decoder with dot-product attention.
//   * scores = src @ (h @ W_att)  -- never materialize src_lin [B,S,H]
//   * single-pass online-softmax attention (K == V == src), src cached as bf16
//     and read with NON-TEMPORAL loads (src has no reuse; protects weights in L3)
//   * bf16 MFMA GEMMs, fp32 cell/readout; LSTM fused into gates-GEMM epilogue;
//     readout(t-1) folded into gates(t) launch as an extra grid plane
// B=256 S=512 E=H=AV=1024 A=TY=128 T=48 NP=97 K_state=2048 K_aty=256
// ---------------------------------------------------------------------------

typedef short s16x8 __attribute__((ext_vector_type(8)));
typedef float f32x4 __attribute__((ext_vector_type(4)));

__device__ __forceinline__ unsigned short f2b(float x) {
  unsigned int u = __float_as_uint(x);
  return (unsigned short)((u + 0x7fffu + ((u >> 16) & 1u)) >> 16);  // RNE
}
__device__ __forceinline__ float b2f(unsigned short h) {
  return __uint_as_float(((unsigned int)h) << 16);
}
__device__ __forceinline__ float sigm(float x) { return 1.f / (1.f + __expf(-x)); }

// ---------------- prep kernels ----------------------------------------------

template <int WRITE_B16>
__global__ __launch_bounds__(256) void pool_convert(const float* __restrict__ src,
                                                    unsigned short* __restrict__ srcb,
                                                    unsigned short* __restrict__ pooledb) {
  int b = blockIdx.x >> 2;
  int e = (blockIdx.x & 3) * 256 + threadIdx.x;
  const float* p = src + (size_t)b * 524288 + e;
  float m = -3e38f;
  for (int s = 0; s < 512; s += 8) {
    float v[8];
#pragma unroll
    for (int i = 0; i < 8; ++i) v[i] = __builtin_nontemporal_load(p + (size_t)(s + i) * 1024);
#pragma unroll
    for (int i = 0; i < 8; ++i) {
      m = fmaxf(m, v[i]);
      if (WRITE_B16) srcb[(size_t)b * 524288 + (size_t)(s + i) * 1024 + e] = f2b(v[i]);
    }
  }
  pooledb[b * 1024 + e] = f2b(m);
}

// Wcat rows permuted n' = j*4+g (g: 0=i,1=f,2=g,3=o); cols = [att|h|a|ty].
__global__ __launch_bounds__(256) void conv_wcat(const float* __restrict__ wih,
                                                 const float* __restrict__ whh,
                                                 unsigned short* __restrict__ wcat) {
  int idx = blockIdx.x * 256 + threadIdx.x;  // 4096*2304
  int np = idx / 2304;
  int k = idx - np * 2304;
  int j = np >> 2, g = np & 3;
  int n = g * 1024 + j;
  float v;
  if (k < 1024) v = wih[n * 1280 + 128 + k];
  else if (k < 2048) v = whh[n * 1024 + (k - 1024)];
  else if (k < 2176) v = wih[n * 1280 + (k - 2048)];
  else v = wih[n * 1280 + 1152 + (k - 2176)];
  wcat[idx] = f2b(v);
}

__global__ __launch_bounds__(256) void conv_bsum(const float* __restrict__ bih,
                                                 const float* __restrict__ bhh,
                                                 float* __restrict__ bsum) {
  int idx = blockIdx.x * 256 + threadIdx.x;  // 4096
  int j = idx >> 2, g = idx & 3;
  int n = g * 1024 + j;
  bsum[idx] = bih[n] + bhh[n];
}

__global__ __launch_bounds__(256) void conv_wattT(const float* __restrict__ watt,
                                                  unsigned short* __restrict__ wt) {
  int idx = blockIdx.x * 256 + threadIdx.x;  // 1024*1024
  int e = idx >> 10, h = idx & 1023;
  wt[idx] = f2b(watt[h * 1024 + e]);
}

__global__ __launch_bounds__(256) void conv_f2b(const float* __restrict__ s,
                                                unsigned short* __restrict__ d, int n) {
  int idx = blockIdx.x * 256 + threadIdx.x;
  if (idx < n) d[idx] = f2b(s[idx]);
}

__global__ __launch_bounds__(256) void conv_wqaT(const float* __restrict__ wqa,
                                                 float* __restrict__ wt) {
  int idx = blockIdx.x * 256 + threadIdx.x;  // 131072
  int k = idx >> 7, j = idx & 127;
  wt[idx] = wqa[j * 1024 + k];
}

__global__ __launch_bounds__(256) void conv_xaty(const int* __restrict__ action,
                                                 const int* __restrict__ type_ids,
                                                 const float* __restrict__ prod_emb,
                                                 const float* __restrict__ type_emb,
                                                 unsigned short* __restrict__ xaty) {
  int idx = blockIdx.x * 256 + threadIdx.x;  // 48*256*256
  int t = idx >> 16;
  int b = (idx >> 8) & 255;
  int kk = idx & 255;
  float v = 0.f;
  if (t > 0) {
    if (kk < 128) v = prod_emb[action[t * 256 + b] * 128 + kk];
    else v = type_emb[type_ids[t * 256 + b] * 128 + (kk - 128)];
  }
  xaty[idx] = f2b(v);
}

__global__ __launch_bounds__(256) void init0(unsigned short* __restrict__ xs0,
                                             float* __restrict__ c) {
  int idx = blockIdx.x * 256 + threadIdx.x;  // 262144
  int b = idx >> 10, e = idx & 1023;
  xs0[(size_t)b * 2048 + e] = 0;
  c[idx] = 0.f;
}

// ---------------- GEMM 64x64 (prep h0 only now) -----------------------------
template <int EPI, int K>
__global__ __launch_bounds__(256) void gemm_bt(const unsigned short* __restrict__ A, int lda,
                                               const unsigned short* __restrict__ B, int ldb,
                                               float* __restrict__ C, int ldc,
                                               const float* __restrict__ bias,
                                               unsigned short* __restrict__ aux, int aux_ld,
                                               int aux_off) {
  int lane = threadIdx.x & 63;
  int wid = threadIdx.x >> 6;
  int mw = blockIdx.y * 64 + (wid >> 1) * 32;
  int nw = blockIdx.x * 64 + (wid & 1) * 32;
  int lr = lane & 15;
  int kg = lane >> 4;
  const unsigned short* a0p = A + (size_t)(mw + lr) * lda + kg * 8;
  const unsigned short* a1p = a0p + (size_t)16 * lda;
  const unsigned short* b0p = B + (size_t)(nw + lr) * ldb + kg * 8;
  const unsigned short* b1p = b0p + (size_t)16 * ldb;
  f32x4 acc00 = {0.f, 0.f, 0.f, 0.f};
  f32x4 acc01 = acc00, acc10 = acc00, acc11 = acc00;
#pragma unroll 4
  for (int k = 0; k < K; k += 32) {
    s16x8 a0 = *(const s16x8*)(a0p + k);
    s16x8 a1 = *(const s16x8*)(a1p + k);
    s16x8 b0 = *(const s16x8*)(b0p + k);
    s16x8 b1 = *(const s16x8*)(b1p + k);
    acc00 = __builtin_amdgcn_mfma_f32_16x16x32_bf16(a0, b0, acc00, 0, 0, 0);
    acc01 = __builtin_amdgcn_mfma_f32_16x16x32_bf16(a0, b1, acc01, 0, 0, 0);
    acc10 = __builtin_amdgcn_mfma_f32_16x16x32_bf16(a1, b0, acc10, 0, 0, 0);
    acc11 = __builtin_amdgcn_mfma_f32_16x16x32_bf16(a1, b1, acc11, 0, 0, 0);
  }
  int r0 = mw + kg * 4;
  int c0 = nw + lr;
#pragma unroll
  for (int fi = 0; fi < 2; ++fi) {
#pragma unroll
    for (int fj = 0; fj < 2; ++fj) {
      f32x4 acc = (fi == 0) ? (fj == 0 ? acc00 : acc01) : (fj == 0 ? acc10 : acc11);
      int rr = r0 + fi * 16;
      int cc = c0 + fj * 16;
#pragma unroll
      for (int r = 0; r < 4; ++r) {
        float v = acc[r];
        if constexpr (EPI == 2) v = tanhf(v + bias[cc]);
        if constexpr (EPI == 1) v = tanhf(v);
        if constexpr (EPI != 0) aux[(size_t)(rr + r) * aux_ld + aux_off + cc] = f2b(v);
        if constexpr (EPI != 2) C[(size_t)(rr + r) * ldc + cc] = v;
      }
    }
  }
}

// ---------------- GEMM 32x32 (q and att: full-chip 256 blocks) --------------
// EPI 0: C fp32.  EPI 1: tanh -> C fp32 + bf16 aux.
template <int EPI, int K>
__global__ __launch_bounds__(256) void gemm32(const unsigned short* __restrict__ A, int lda,
                                              const unsigned short* __restrict__ B, int ldb,
                                              float* __restrict__ C, int ldc,
                                              unsigned short* __restrict__ aux, int aux_ld,
                                              int aux_off) {
  int lane = threadIdx.x & 63;
  int wid = threadIdx.x >> 6;
  int mw = blockIdx.y * 32 + (wid >> 1) * 16;
  int nw = blockIdx.x * 32 + (wid & 1) * 16;
  int lr = lane & 15;
  int kg = lane >> 4;
  const unsigned short* ap = A + (size_t)(mw + lr) * lda + kg * 8;
  const unsigned short* bp = B + (size_t)(nw + lr) * ldb + kg * 8;
  f32x4 acc = {0.f, 0.f, 0.f, 0.f};
#pragma unroll 8
  for (int k = 0; k < K; k += 32) {
    s16x8 a = *(const s16x8*)(ap + k);
    s16x8 b = *(const s16x8*)(bp + k);
    acc = __builtin_amdgcn_mfma_f32_16x16x32_bf16(a, b, acc, 0, 0, 0);
  }
  int rr = mw + kg * 4;
  int cc = nw + lr;
#pragma unroll
  for (int r = 0; r < 4; ++r) {
    float v = acc[r];
    if constexpr (EPI == 1) {
      v = tanhf(v);
      aux[(size_t)(rr + r) * aux_ld + aux_off + cc] = f2b(v);
    }
    C[(size_t)(rr + r) * ldc + cc] = v;
  }
}

// ---------------- gates GEMM + fused LSTM + piggybacked readout(t-1) --------
// grid (64,5): y<4 GEMM+LSTM (tile 64b x 64gate), y==4: readout for t-1.
__global__ __launch_bounds__(256) void gates_fused(const unsigned short* __restrict__ xin,
                                                   const unsigned short* __restrict__ xaty,
                                                   const unsigned short* __restrict__ wcat,
                                                   const float* __restrict__ bsum,
                                                   float* __restrict__ cbuf,
                                                   unsigned short* __restrict__ xout,
                                                   unsigned short* __restrict__ a2,
                                                   const float* __restrict__ attf,
                                                   const float* __restrict__ wqaT,
                                                   const float* __restrict__ b_qa,
                                                   const float* __restrict__ prod_emb,
                                                   const float* __restrict__ prod_bias,
                                                   float* __restrict__ out, int t) {
  __shared__ float ld[64][68];
  __shared__ float s_att[2][1024];
  __shared__ float s_q2[2][128];
  __shared__ float s_log[2][100];
  __shared__ float s_red[2][2];

  if (blockIdx.y == 4) {
    // ---- readout for step t-1, 4 batches per block ----
    if (t == 0) return;
    int half = threadIdx.x >> 7;
    int ltid = threadIdx.x & 127;
#pragma unroll
    for (int rep = 0; rep < 2; ++rep) {
      int b = blockIdx.x * 4 + rep * 2 + half;
      const float* ap = attf + (size_t)b * 1024;
      for (int i = ltid; i < 1024; i += 128) s_att[half][i] = ap[i];
      __syncthreads();
      float acc = b_qa[ltid];
      for (int k = 0; k < 1024; ++k) acc += s_att[half][k] * wqaT[k * 128 + ltid];
      s_q2[half][ltid] = tanhf(acc);
      __syncthreads();
      if (ltid < 97) {
        float a = prod_bias[ltid];
        const float* pe = prod_emb + ltid * 128;
        float aa = 0.f;
        for (int k = 0; k < 128; ++k) aa += s_q2[half][k] * pe[k];
        s_log[half][ltid] = a + aa;
      }
      __syncthreads();
      if (ltid == 0) {
        float M = s_log[half][0];
        for (int k2 = 1; k2 < 97; ++k2) M = fmaxf(M, s_log[half][k2]);
        float D = 0.f;
        for (int k2 = 0; k2 < 97; ++k2) D += __expf(s_log[half][k2] - M);
        s_red[half][0] = M;
        s_red[half][1] = D;
      }
      __syncthreads();
      if (ltid < 97)
        out[((size_t)(t - 1) * 256 + b) * 97 + ltid] =
            __expf(s_log[half][ltid] - s_red[half][0]) / s_red[half][1];
      __syncthreads();
    }
    return;
  }

  int lane = threadIdx.x & 63;
  int wid = threadIdx.x >> 6;
  int mwl = (wid >> 1) * 32;
  int nwl = (wid & 1) * 32;
  int mw = blockIdx.y * 64 + mwl;
  int nw = blockIdx.x * 64 + nwl;
  int lr = lane & 15;
  int kg = lane >> 4;
  const unsigned short* a0p = xin + (size_t)(mw + lr) * 2048 + kg * 8;
  const unsigned short* a1p = a0p + (size_t)16 * 2048;
  const unsigned short* b0p = wcat + (size_t)(nw + lr) * 2304 + kg * 8;
  const unsigned short* b1p = b0p + (size_t)16 * 2304;
  f32x4 acc00 = {0.f, 0.f, 0.f, 0.f};
  f32x4 acc01 = acc00, acc10 = acc00, acc11 = acc00;
#pragma unroll 8
  for (int k = 0; k < 2048; k += 32) {
    s16x8 a0 = *(const s16x8*)(a0p + k);
    s16x8 a1 = *(const s16x8*)(a1p + k);
    s16x8 b0 = *(const s16x8*)(b0p + k);
    s16x8 b1 = *(const s16x8*)(b1p + k);
    acc00 = __builtin_amdgcn_mfma_f32_16x16x32_bf16(a0, b0, acc00, 0, 0, 0);
    acc01 = __builtin_amdgcn_mfma_f32_16x16x32_bf16(a0, b1, acc01, 0, 0, 0);
    acc10 = __builtin_amdgcn_mfma_f32_16x16x32_bf16(a1, b0, acc10, 0, 0, 0);
    acc11 = __builtin_amdgcn_mfma_f32_16x16x32_bf16(a1, b1, acc11, 0, 0, 0);
  }
  const unsigned short* c0p = xaty + (size_t)(mw + lr) * 256 + kg * 8;
  const unsigned short* c1p = c0p + (size_t)16 * 256;
#pragma unroll
  for (int k = 0; k < 256; k += 32) {
    s16x8 a0 = *(const s16x8*)(c0p + k);
    s16x8 a1 = *(const s16x8*)(c1p + k);
    s16x8 b0 = *(const s16x8*)(b0p + 2048 + k);
    s16x8 b1 = *(const s16x8*)(b1p + 2048 + k);
    acc00 = __builtin_amdgcn_mfma_f32_16x16x32_bf16(a0, b0, acc00, 0, 0, 0);
    acc01 = __builtin_amdgcn_mfma_f32_16x16x32_bf16(a0, b1, acc01, 0, 0, 0);
    acc10 = __builtin_amdgcn_mfma_f32_16x16x32_bf16(a1, b0, acc10, 0, 0, 0);
    acc11 = __builtin_amdgcn_mfma_f32_16x16x32_bf16(a1, b1, acc11, 0, 0, 0);
  }
  int r0 = mwl + kg * 4;
  int c0 = nwl + lr;
#pragma unroll
  for (int fi = 0; fi < 2; ++fi)
#pragma unroll
    for (int fj = 0; fj < 2; ++fj) {
      f32x4 acc = (fi == 0) ? (fj == 0 ? acc00 : acc01) : (fj == 0 ? acc10 : acc11);
#pragma unroll
      for (int r = 0; r < 4; ++r) ld[r0 + fi * 16 + r][c0 + fj * 16] = acc[r];
    }
  __syncthreads();
  int row = threadIdx.x >> 2;
  int col0 = (threadIdx.x & 3) * 16;
  int b = blockIdx.y * 64 + row;
  int jbase = blockIdx.x * 16 + (threadIdx.x & 3) * 4;
  float4 cold = *(const float4*)(cbuf + (size_t)b * 1024 + jbase);
  float cn[4];
  unsigned short hb[4];
#pragma unroll
  for (int i = 0; i < 4; ++i) {
    float4 bs = *(const float4*)(bsum + (size_t)(jbase + i) * 4);
    float vi = ld[row][col0 + 4 * i + 0] + bs.x;
    float vf = ld[row][col0 + 4 * i + 1] + bs.y;
    float vg = ld[row][col0 + 4 * i + 2] + bs.z;
    float vo = ld[row][col0 + 4 * i + 3] + bs.w;
    float co = (i == 0) ? cold.x : (i == 1) ? cold.y : (i == 2) ? cold.z : cold.w;
    float ct = sigm(vf) * co + sigm(vi) * tanhf(vg);
    float ht = sigm(vo) * tanhf(ct);
    cn[i] = ct;
    hb[i] = f2b(ht);
  }
  *(float4*)(cbuf + (size_t)b * 1024 + jbase) = make_float4(cn[0], cn[1], cn[2], cn[3]);
  ushort4 h4 = make_ushort4(hb[0], hb[1], hb[2], hb[3]);
  *(ushort4*)(xout + (size_t)b * 2048 + 1024 + jbase) = h4;
  *(ushort4*)(a2 + (size_t)b * 2048 + jbase) = h4;
}

// ---------------- flash attention (single pass, nt src loads) ---------------
template <int BF16P>
__global__ __launch_bounds__(1024) void flash_attn(const unsigned short* __restrict__ srcb,
                                                   const float* __restrict__ srcf,
                                                   const float* __restrict__ q,
                                                   unsigned short* __restrict__ a2) {
  __shared__ unsigned short lctx[16][1024];
  __shared__ float lm[16], ldn[16], lsc[16];
  __shared__ float sDinv;
  int b = blockIdx.x;
  int wid = threadIdx.x >> 6, lane = threadIdx.x & 63;
  float qr[16];
  {
    const float4* qp = (const float4*)(q + (size_t)b * 1024 + lane * 16);
#pragma unroll
    for (int i = 0; i < 4; ++i) {
      float4 t = qp[i];
      qr[4 * i] = t.x; qr[4 * i + 1] = t.y; qr[4 * i + 2] = t.z; qr[4 * i + 3] = t.w;
    }
  }
  float m = -3e38f, d = 0.f;
  float ctx[16];
#pragma unroll
  for (int i = 0; i < 16; ++i) ctx[i] = 0.f;
  int s0 = wid * 32;

  if (BF16P) {
    const unsigned short* rb = srcb + (size_t)b * 524288 + lane * 16;
    s16x8 u0 = __builtin_nontemporal_load((const s16x8*)(rb + (size_t)s0 * 1024));
    s16x8 u1 = __builtin_nontemporal_load((const s16x8*)(rb + (size_t)s0 * 1024 + 8));
    for (int s = 0; s < 32; ++s) {
      int rn = s0 + s + 1;
      rn = rn > 511 ? 511 : rn;
      s16x8 n0 = __builtin_nontemporal_load((const s16x8*)(rb + (size_t)rn * 1024));
      s16x8 n1 = __builtin_nontemporal_load((const s16x8*)(rb + (size_t)rn * 1024 + 8));
      float v[16];
#pragma unroll
      for (int i = 0; i < 8; ++i) {
        v[i] = b2f((unsigned short)u0[i]);
        v[8 + i] = b2f((unsigned short)u1[i]);
      }
      float sc = 0.f;
#pragma unroll
      for (int i = 0; i < 16; ++i) sc += v[i] * qr[i];
#pragma unroll
      for (int off = 1; off < 64; off <<= 1) sc += __shfl_xor(sc, off);
      float mn = fmaxf(m, sc);
      float scale = __expf(m - mn);
      float wgt = __expf(sc - mn);
      d = d * scale + wgt;
#pragma unroll
      for (int i = 0; i < 16; ++i) ctx[i] = ctx[i] * scale + wgt * v[i];
      m = mn;
      u0 = n0; u1 = n1;
    }
  } else {
    const float* rb = srcf + (size_t)b * 524288 + lane * 16;
    for (int s = 0; s < 32; ++s) {
      int r = s0 + s;
      float v[16];
#pragma unroll
      for (int i = 0; i < 4; ++i) {
        f32x4 t = __builtin_nontemporal_load((const f32x4*)(rb + (size_t)r * 1024 + 4 * i));
        v[4 * i] = t[0]; v[4 * i + 1] = t[1]; v[4 * i + 2] = t[2]; v[4 * i + 3] = t[3];
      }
      float sc = 0.f;
#pragma unroll
      for (int i = 0; i < 16; ++i) sc += v[i] * qr[i];
#pragma unroll
      for (int off = 1; off < 64; off <<= 1) sc += __shfl_xor(sc, off);
      float mn = fmaxf(m, sc);
      float scale = __expf(m - mn);
      float wgt = __expf(sc - mn);
      d = d * scale + wgt;
#pragma unroll
      for (int i = 0; i < 16; ++i) ctx[i] = ctx[i] * scale + wgt * v[i];
      m = mn;
    }
  }

#pragma unroll
  for (int i = 0; i < 16; ++i) lctx[wid][lane * 16 + i] = f2b(ctx[i]);
  if (lane == 0) { lm[wid] = m; ldn[wid] = d; }
  __syncthreads();
  if (threadIdx.x == 0) {
    float M = lm[0];
    for (int w2 = 1; w2 < 16; ++w2) M = fmaxf(M, lm[w2]);
    float D = 0.f;
    for (int w2 = 0; w2 < 16; ++w2) {
      float sc = __expf(lm[w2] - M);
      lsc[w2] = sc;
      D += sc * ldn[w2];
    }
    sDinv = 1.f / D;
  }
  __syncthreads();
  int e = threadIdx.x;
  float acc = 0.f;
#pragma unroll
  for (int w2 = 0; w2 < 16; ++w2) acc += lsc[w2] * b2f(lctx[w2][e]);
  a2[(size_t)b * 2048 + 1024 + e] = f2b(acc * sDinv);
}

// ---------------- standalone readout (final step only) ----------------------
__global__ __launch_bounds__(128) void readout(const float* __restrict__ att,
                                               const float* __restrict__ wqaT,
                                               const float* __restrict__ b_qa,
                                               const float* __restrict__ prod_emb,
                                               const float* __restrict__ prod_bias,
                                               float* __restrict__ out, int t) {
  __shared__ float s_att[1024], s_q2[128], s_log[97], s_red[2];
  int b = blockIdx.x;
  int tid = threadIdx.x;
  for (int i = tid; i < 1024; i += 128) s_att[i] = att[(size_t)b * 1024 + i];
  __syncthreads();
  float acc = b_qa[tid];
  for (int k = 0; k < 1024; ++k) acc += s_att[k] * wqaT[k * 128 + tid];
  s_q2[tid] = tanhf(acc);
  __syncthreads();
  if (tid < 97) {
    float a = prod_bias[tid];
    const float* pe = prod_emb + tid * 128;
    for (int k = 0; k < 128; ++k) a += s_q2[k] * pe[k];
    s_log[tid] = a;
  }
  __syncthreads();
  if (tid == 0) {
    float M = s_log[0];
    for (int k = 1; k < 97; ++k) M = fmaxf(M, s_log[k]);
    float D = 0.f;
    for (int k = 0; k < 97; ++k) D += __expf(s_log[k] - M);
    s_red[0] = M;
    s_red[1] = D;
  }
  __syncthreads();
  if (tid < 97)
    out[((size_t)t * 256 + b) * 97 + tid] = __expf(s_log[tid] - s_red[0]) / s_red[1];
}

// ---------------------------------------------------------------------------

extern "C" void kernel_launch(void* const* d_in, const int* in_sizes, int n_in,
                              void* d_out, int out_size, void* d_ws, size_t ws_size,
                              hipStream_t stream) {
  const float* src = (const float*)d_in[0];
  const int* action = (const int*)d_in[1];
  const int* type_ids = (const int*)d_in[2];
  const float* W_ih = (const float*)d_in[3];
  const float* b_ih = (const float*)d_in[4];
  const float* W_hh = (const float*)d_in[5];
  const float* b_hh = (const float*)d_in[6];
  const float* W_att = (const float*)d_in[7];
  const float* W_av = (const float*)d_in[8];
  const float* W_qa = (const float*)d_in[9];
  const float* b_qa = (const float*)d_in[10];
  const float* prod_emb = (const float*)d_in[11];
  const float* prod_bias = (const float*)d_in[12];
  const float* type_emb = (const float*)d_in[13];
  const float* W_init = (const float*)d_in[14];
  const float* b_init = (const float*)d_in[15];
  float* out = (float*)d_out;

  const size_t NEED_SMALL = 40910848ull;
  const size_t NEED_BIG = 309346304ull;
  bool big = ws_size >= NEED_BIG;
  if (!big && ws_size < NEED_SMALL) return;

  char* w = (char*)d_ws;
  size_t o = 0;
  unsigned short* wcat = (unsigned short*)(w + o); o += 18874368ull;
  unsigned short* wattT = (unsigned short*)(w + o); o += 2097152ull;
  unsigned short* wav = (unsigned short*)(w + o); o += 4194304ull;
  float* wqaT = (float*)(w + o); o += 524288ull;
  unsigned short* xaty = (unsigned short*)(w + o); o += 6291456ull;
  unsigned short* xstate0 = (unsigned short*)(w + o); o += 1048576ull;
  unsigned short* xstate1 = (unsigned short*)(w + o); o += 1048576ull;
  unsigned short* a2 = (unsigned short*)(w + o); o += 1048576ull;
  float* cbuf = (float*)(w + o); o += 1048576ull;
  float* qbuf = (float*)(w + o); o += 1048576ull;
  float* attf = (float*)(w + o); o += 1048576ull;
  unsigned short* pooledb = (unsigned short*)(w + o); o += 524288ull;
  unsigned short* winitb = (unsigned short*)(w + o); o += 2097152ull;
  float* bsum = (float*)(w + o); o += 16384ull;
  unsigned short* srcb = nullptr;
  if (big) { srcb = (unsigned short*)(w + o); o += 268435456ull; }

  // ---- prep ----
  if (big) pool_convert<1><<<1024, 256, 0, stream>>>(src, srcb, pooledb);
  else     pool_convert<0><<<1024, 256, 0, stream>>>(src, nullptr, pooledb);
  conv_wcat<<<36864, 256, 0, stream>>>(W_ih, W_hh, wcat);
  conv_bsum<<<16, 256, 0, stream>>>(b_ih, b_hh, bsum);
  conv_wattT<<<4096, 256, 0, stream>>>(W_att, wattT);
  conv_f2b<<<8192, 256, 0, stream>>>(W_av, wav, 2097152);
  conv_f2b<<<4096, 256, 0, stream>>>(W_init, winitb, 1048576);
  conv_wqaT<<<512, 256, 0, stream>>>(W_qa, wqaT);
  conv_xaty<<<12288, 256, 0, stream>>>(action, type_ids, prod_emb, type_emb, xaty);
  init0<<<1024, 256, 0, stream>>>(xstate0, cbuf);
  gemm_bt<2, 1024><<<dim3(16, 4), 256, 0, stream>>>(pooledb, 1024, winitb, 1024,
                                                    nullptr, 0, b_init, xstate0, 2048, 1024);

  // ---- 48 recurrent steps (4 nodes each; readout(t-1) rides gates(t)) ----
  for (int t = 0; t < 48; ++t) {
    const unsigned short* xin = (t & 1) ? xstate1 : xstate0;
    unsigned short* xout = (t & 1) ? xstate0 : xstate1;
    gates_fused<<<dim3(64, 5), 256, 0, stream>>>(xin, xaty + (size_t)t * 65536, wcat, bsum,
                                                 cbuf, xout, a2, attf, wqaT, b_qa, prod_emb,
                                                 prod_bias, out, t);
    gemm32<0, 1024><<<dim3(32, 8), 256, 0, stream>>>(a2, 2048, wattT, 1024, qbuf, 1024,
                                                     nullptr, 0, 0);
    if (big) flash_attn<1><<<256, 1024, 0, stream>>>(srcb, nullptr, qbuf, a2);
    else     flash_attn<0><<<256, 1024, 0, stream>>>(nullptr, src, qbuf, a2);
    gemm32<1, 2048><<<dim3(32, 8), 256, 0, stream>>>(a2, 2048, wav, 2048, attf, 1024,
                                                     xout, 2048, 0);
  }
  readout<<<256, 128, 0, stream>>>(attf, wqaT, b_qa, prod_emb, prod_bias, out, 47);
}